// Round 2
// baseline (10618.682 us; speedup 1.0000x reference)
//
#include <hip/hip_runtime.h>
#include <hip/hip_bf16.h>

#define NEG_SLOPE 0.1f

// ---------------- direct conv + leaky relu ----------------
// grid: x = spatial tiles of 256, z = B*Cout  (weights wave-uniform per block -> scalar cache)
template <int K, int STRIDE>
__global__ void conv_lrelu(const float* __restrict__ x, const float* __restrict__ w,
                           const float* __restrict__ bs, float* __restrict__ y,
                           int Cin, int Hin, int Win, int Cout, int Hout, int Wout,
                           int pad) {
    int sp = blockIdx.x * blockDim.x + threadIdx.x;
    int HWo = Hout * Wout;
    if (sp >= HWo) return;
    int bc = blockIdx.z;
    int b = bc / Cout;
    int co = bc % Cout;
    int ho = sp / Wout;
    int wo = sp % Wout;

    const float* xb = x + (size_t)b * Cin * Hin * Win;
    const float* wc = w + (size_t)co * Cin * K * K;
    float acc = bs[co];
    int hi0 = ho * STRIDE - pad;
    int wi0 = wo * STRIDE - pad;

    for (int ci = 0; ci < Cin; ++ci) {
        const float* xc = xb + (size_t)ci * Hin * Win;
        const float* wk = wc + ci * K * K;
#pragma unroll
        for (int kh = 0; kh < K; ++kh) {
            int hi = hi0 + kh;
            if ((unsigned)hi >= (unsigned)Hin) continue;
            const float* xr = xc + (size_t)hi * Win;
#pragma unroll
            for (int kw = 0; kw < K; ++kw) {
                int wi = wi0 + kw;
                float xv = ((unsigned)wi < (unsigned)Win) ? xr[wi] : 0.0f;
                acc = fmaf(xv, wk[kh * K + kw], acc);
            }
        }
    }
    acc = (acc >= 0.0f) ? acc : NEG_SLOPE * acc;
    y[(size_t)bc * HWo + sp] = acc;
}

// ---------------- bilinear warp (B=4, H=12, W=24) ----------------
__global__ void warp_kernel(const float* __restrict__ img, const float* __restrict__ flow,
                            float* __restrict__ out, int C) {
    const int H = 12, W = 24, HW = 288;
    int idx = blockIdx.x * blockDim.x + threadIdx.x;
    int total = 4 * C * HW;
    if (idx >= total) return;
    int w = idx % W;
    int h = (idx / W) % H;
    int c = (idx / HW) % C;
    int b = idx / (HW * C);

    float fx = flow[(((size_t)b * 2 + 0) * H + h) * W + w] * 0.625f;
    float fy = flow[(((size_t)b * 2 + 1) * H + h) * W + w] * 0.625f;
    float px = (float)w + fx;
    float py = (float)h + fy;
    float x0f = floorf(px);
    float y0f = floorf(py);
    float wx = px - x0f;
    float wy = py - y0f;
    int x0 = (int)x0f;
    int y0 = (int)y0f;

    const float* ip = img + ((size_t)b * C + c) * HW;
    auto g = [&](int yi, int xi) -> float {
        if (xi < 0 || xi > W - 1 || yi < 0 || yi > H - 1) return 0.0f;
        return ip[yi * W + xi];
    };
    float v = g(y0, x0) * (1.0f - wx) * (1.0f - wy)
            + g(y0, x0 + 1) * wx * (1.0f - wy)
            + g(y0 + 1, x0) * (1.0f - wx) * wy
            + g(y0 + 1, x0 + 1) * wx * wy;
    out[idx] = v;
}

// ---------------- correlation (7x7 disp) + lrelu -> f32 out ----------------
__global__ void corr_lrelu(const float* __restrict__ f1, const float* __restrict__ wp,
                           float* __restrict__ out, int C) {
    const int H = 12, W = 24, HW = 288;
    int idx = blockIdx.x * blockDim.x + threadIdx.x;
    int total = 4 * 49 * HW;
    if (idx >= total) return;
    int w = idx % W;
    int h = (idx / W) % H;
    int d = (idx / HW) % 49;
    int b = idx / (49 * HW);
    int di = d / 7 - 3;
    int dj = d % 7 - 3;
    int h2 = h + di;
    int w2 = w + dj;

    float s = 0.0f;
    if (h2 >= 0 && h2 < H && w2 >= 0 && w2 < W) {
        const float* a = f1 + (size_t)b * C * HW + h * W + w;
        const float* p = wp + (size_t)b * C * HW + h2 * W + w2;
        for (int c = 0; c < C; ++c) s = fmaf(a[(size_t)c * HW], p[(size_t)c * HW], s);
    }
    s /= (float)C;
    s = (s >= 0.0f) ? s : NEG_SLOPE * s;
    out[idx] = s;
}

// ---------------- host ----------------
static inline int cdiv(int a, int b) { return (a + b - 1) / b; }

extern "C" void kernel_launch(void* const* d_in, const int* in_sizes, int n_in,
                              void* d_out, int out_size, void* d_ws, size_t ws_size,
                              hipStream_t stream) {
    const float* img1 = (const float*)d_in[0];
    const float* img2 = (const float*)d_in[1];
    const float* flow = (const float*)d_in[2];
    float* out = (float*)d_out;

    // weights/biases straight from inputs (fp32)
    const float* W[10];
    const float* Bs[10];
    for (int l = 0; l < 10; ++l) {
        W[l]  = (const float*)d_in[3 + 2 * l];
        Bs[l] = (const float*)d_in[4 + 2 * l];
    }

    // workspace layout (floats): bufA 37.75M, bufB 9.44M, f1/f2/wrp 221k each
    float* ws = (float*)d_ws;
    size_t off = 0;
    float* bufA = ws + off; off += 37748736;  // 4*32*384*768
    float* bufB = ws + off; off += 9437184;   // 4*32*192*384
    float* f1   = ws + off; off += 221184;    // 4*192*12*24
    float* f2   = ws + off; off += 221184;
    float* wrp  = ws + off; off += 221184;

    auto chain = [&](const float* img, float* fout) {
        // L1: 3->32, 7x7 s1 p3, 384x768
        conv_lrelu<7, 1><<<dim3(cdiv(384 * 768, 256), 1, 4 * 32), 256, 0, stream>>>(
            img, W[0], Bs[0], bufA, 3, 384, 768, 32, 384, 768, 3);
        // L2: 32->32, 3x3 s2 p1, ->192x384
        conv_lrelu<3, 2><<<dim3(cdiv(192 * 384, 256), 1, 4 * 32), 256, 0, stream>>>(
            bufA, W[1], Bs[1], bufB, 32, 384, 768, 32, 192, 384, 1);
        // L3: 32->32, s1
        conv_lrelu<3, 1><<<dim3(cdiv(192 * 384, 256), 1, 4 * 32), 256, 0, stream>>>(
            bufB, W[2], Bs[2], bufA, 32, 192, 384, 32, 192, 384, 1);
        // L4: 32->32, s1
        conv_lrelu<3, 1><<<dim3(cdiv(192 * 384, 256), 1, 4 * 32), 256, 0, stream>>>(
            bufA, W[3], Bs[3], bufB, 32, 192, 384, 32, 192, 384, 1);
        // L5: 32->64, s2, ->96x192
        conv_lrelu<3, 2><<<dim3(cdiv(96 * 192, 256), 1, 4 * 64), 256, 0, stream>>>(
            bufB, W[4], Bs[4], bufA, 32, 192, 384, 64, 96, 192, 1);
        // L6: 64->64, s1
        conv_lrelu<3, 1><<<dim3(cdiv(96 * 192, 256), 1, 4 * 64), 256, 0, stream>>>(
            bufA, W[5], Bs[5], bufB, 64, 96, 192, 64, 96, 192, 1);
        // L7: 64->96, s2, ->48x96
        conv_lrelu<3, 2><<<dim3(cdiv(48 * 96, 256), 1, 4 * 96), 256, 0, stream>>>(
            bufB, W[6], Bs[6], bufA, 64, 96, 192, 96, 48, 96, 1);
        // L8: 96->96, s1
        conv_lrelu<3, 1><<<dim3(cdiv(48 * 96, 256), 1, 4 * 96), 256, 0, stream>>>(
            bufA, W[7], Bs[7], bufB, 96, 48, 96, 96, 48, 96, 1);
        // L9: 96->128, s2, ->24x48
        conv_lrelu<3, 2><<<dim3(cdiv(24 * 48, 256), 1, 4 * 128), 256, 0, stream>>>(
            bufB, W[8], Bs[8], bufA, 96, 48, 96, 128, 24, 48, 1);
        // L10: 128->192, s2, ->12x24
        conv_lrelu<3, 2><<<dim3(cdiv(12 * 24, 256), 1, 4 * 192), 256, 0, stream>>>(
            bufA, W[9], Bs[9], fout, 128, 24, 48, 192, 12, 24, 1);
    };

    chain(img1, f1);
    chain(img2, f2);

    // warp f2 by flow*0.625
    warp_kernel<<<cdiv(4 * 192 * 288, 256), 256, 0, stream>>>(f2, flow, wrp, 192);

    // correlation + lrelu
    corr_lrelu<<<cdiv(4 * 49 * 288, 256), 256, 0, stream>>>(f1, wrp, out, 192);
}

// Round 3
// 3121.414 us; speedup vs baseline: 3.4019x; 3.4019x over previous
//
#include <hip/hip_runtime.h>

#define NEG_SLOPE 0.1f

static inline int cdiv(int a, int b) { return (a + b - 1) / b; }

// ---------------- blocked direct conv + leaky relu ----------------
// Each thread: TCO output channels x TW output columns.
// Block of 256 threads covers 256*TW spatial outputs; blockIdx.z = b * (COUT/TCO) + co_group.
// Weights for the block's TCO channels staged in LDS ([ci][kh][kw][t], uniform-address reads -> broadcast).
template <int K, int S, int PAD, int CIN, int COUT,
          int HIN, int WIN, int HOUT, int WOUT, int TCO, int TW>
__global__ __launch_bounds__(256) void conv_blk(const float* __restrict__ x,
                                                const float* __restrict__ w,
                                                const float* __restrict__ bs,
                                                float* __restrict__ y) {
    constexpr int SLOTS_W = WOUT / TW;      // thread-slots per output row
    constexpr int NSLOT   = HOUT * SLOTS_W; // thread-slots per (b, co_group) plane
    constexpr int NW      = TCO * CIN * K * K;

    __shared__ float wlds[NW];

    const int zz  = blockIdx.z;
    const int b   = zz / (COUT / TCO);
    const int cob = (zz % (COUT / TCO)) * TCO;

    // stage weights: wlds[((ci*K+kh)*K+kw)*TCO + t] = w[(cob+t)][ci][kh][kw]
    for (int i = threadIdx.x; i < NW; i += 256) {
        int t    = i % TCO;
        int rest = i / TCO;                 // = ci*K*K + kh*K + kw
        wlds[i] = w[(size_t)(cob + t) * (CIN * K * K) + rest];
    }
    __syncthreads();

    const int slot = blockIdx.x * 256 + threadIdx.x;
    if (slot >= NSLOT) return;

    const int ho = slot / SLOTS_W;
    const int wo = (slot % SLOTS_W) * TW;

    const float* xb = x + (size_t)b * CIN * HIN * WIN;

    float acc[TCO][TW];
#pragma unroll
    for (int t = 0; t < TCO; ++t) {
        float bv = bs[cob + t];
#pragma unroll
        for (int j = 0; j < TW; ++j) acc[t][j] = bv;
    }

    const int hi0 = ho * S - PAD;
    const int wi0 = wo * S - PAD;
    constexpr int L = (TW - 1) * S + K;     // input columns needed per row
    const bool interior = (hi0 >= 0) && (hi0 + K <= HIN) && (wi0 >= 0) && (wi0 + L <= WIN);

    for (int ci = 0; ci < CIN; ++ci) {
        const float* xc = xb + (size_t)ci * HIN * WIN;
        const float* wc = &wlds[(ci * K * K) * TCO];
#pragma unroll
        for (int kh = 0; kh < K; ++kh) {
            const int hi = hi0 + kh;
            float r[L];
            if (interior) {
                const float* xr = xc + (size_t)hi * WIN + wi0;
#pragma unroll
                for (int u = 0; u < L; ++u) r[u] = xr[u];
            } else {
                const bool rowok = (unsigned)hi < (unsigned)HIN;
#pragma unroll
                for (int u = 0; u < L; ++u) {
                    const int wi = wi0 + u;
                    r[u] = (rowok && (unsigned)wi < (unsigned)WIN)
                               ? xc[(size_t)hi * WIN + wi] : 0.0f;
                }
            }
#pragma unroll
            for (int kw = 0; kw < K; ++kw) {
                const float* wg = wc + (kh * K + kw) * TCO;
                float w8[TCO];
#pragma unroll
                for (int t = 0; t < TCO; ++t) w8[t] = wg[t];
#pragma unroll
                for (int j = 0; j < TW; ++j) {
                    const float xv = r[kw + j * S];
#pragma unroll
                    for (int t = 0; t < TCO; ++t)
                        acc[t][j] = fmaf(xv, w8[t], acc[t][j]);
                }
            }
        }
    }

    // epilogue: leaky relu + vectorized store (wo multiple of TW, WOUT multiple of TW)
#pragma unroll
    for (int t = 0; t < TCO; ++t) {
        float* yr = y + (((size_t)b * COUT + cob + t) * HOUT + ho) * WOUT + wo;
#pragma unroll
        for (int j = 0; j < TW; ++j) {
            const float v = acc[t][j];
            yr[j] = v >= 0.0f ? v : NEG_SLOPE * v;
        }
    }
}

// ---------------- bilinear warp (B=4, H=12, W=24) ----------------
__global__ void warp_kernel(const float* __restrict__ img, const float* __restrict__ flow,
                            float* __restrict__ out, int C) {
    const int H = 12, W = 24, HW = 288;
    int idx = blockIdx.x * blockDim.x + threadIdx.x;
    int total = 4 * C * HW;
    if (idx >= total) return;
    int w = idx % W;
    int h = (idx / W) % H;
    int c = (idx / HW) % C;
    int b = idx / (HW * C);

    float fx = flow[(((size_t)b * 2 + 0) * H + h) * W + w] * 0.625f;
    float fy = flow[(((size_t)b * 2 + 1) * H + h) * W + w] * 0.625f;
    float px = (float)w + fx;
    float py = (float)h + fy;
    float x0f = floorf(px);
    float y0f = floorf(py);
    float wx = px - x0f;
    float wy = py - y0f;
    int x0 = (int)x0f;
    int y0 = (int)y0f;

    const float* ip = img + ((size_t)b * C + c) * HW;
    auto g = [&](int yi, int xi) -> float {
        if (xi < 0 || xi > W - 1 || yi < 0 || yi > H - 1) return 0.0f;
        return ip[yi * W + xi];
    };
    float v = g(y0, x0) * (1.0f - wx) * (1.0f - wy)
            + g(y0, x0 + 1) * wx * (1.0f - wy)
            + g(y0 + 1, x0) * (1.0f - wx) * wy
            + g(y0 + 1, x0 + 1) * wx * wy;
    out[idx] = v;
}

// ---------------- correlation (7x7 disp) + lrelu ----------------
__global__ void corr_lrelu(const float* __restrict__ f1, const float* __restrict__ wp,
                           float* __restrict__ out, int C) {
    const int H = 12, W = 24, HW = 288;
    int idx = blockIdx.x * blockDim.x + threadIdx.x;
    int total = 4 * 49 * HW;
    if (idx >= total) return;
    int w = idx % W;
    int h = (idx / W) % H;
    int d = (idx / HW) % 49;
    int b = idx / (49 * HW);
    int di = d / 7 - 3;
    int dj = d % 7 - 3;
    int h2 = h + di;
    int w2 = w + dj;

    float s = 0.0f;
    if (h2 >= 0 && h2 < H && w2 >= 0 && w2 < W) {
        const float* a = f1 + (size_t)b * C * HW + h * W + w;
        const float* p = wp + (size_t)b * C * HW + h2 * W + w2;
        for (int c = 0; c < C; ++c) s = fmaf(a[(size_t)c * HW], p[(size_t)c * HW], s);
    }
    s /= (float)C;
    s = (s >= 0.0f) ? s : NEG_SLOPE * s;
    out[idx] = s;
}

// ---------------- host ----------------
extern "C" void kernel_launch(void* const* d_in, const int* in_sizes, int n_in,
                              void* d_out, int out_size, void* d_ws, size_t ws_size,
                              hipStream_t stream) {
    const float* img1 = (const float*)d_in[0];
    const float* img2 = (const float*)d_in[1];
    const float* flow = (const float*)d_in[2];
    float* out = (float*)d_out;

    const float* W[10];
    const float* Bs[10];
    for (int l = 0; l < 10; ++l) {
        W[l]  = (const float*)d_in[3 + 2 * l];
        Bs[l] = (const float*)d_in[4 + 2 * l];
    }

    // ws layout identical to the proven round-2 footprint (47.85M floats = 191.4 MB)
    float* ws = (float*)d_ws;
    size_t off = 0;
    float* bufA = ws + off; off += 37748736;  // 4*32*384*768
    float* bufB = ws + off; off += 9437184;   // 4*32*192*384
    float* f1   = ws + off; off += 221184;    // 4*192*12*24
    float* f2   = ws + off; off += 221184;
    float* wrp  = ws + off; off += 221184;

    auto chain = [&](const float* img, float* fout) {
        // L1: 3->32, 7x7 s1 p3, 384x768
        conv_blk<7,1,3,  3, 32, 384,768, 384,768, 8,4>
            <<<dim3(cdiv(384*(768/4),256),1,4*(32/8)), 256, 0, stream>>>(img,  W[0], Bs[0], bufA);
        // L2: 32->32, 3x3 s2 p1 -> 192x384
        conv_blk<3,2,1, 32, 32, 384,768, 192,384, 8,4>
            <<<dim3(cdiv(192*(384/4),256),1,4*(32/8)), 256, 0, stream>>>(bufA, W[1], Bs[1], bufB);
        // L3: 32->32, s1
        conv_blk<3,1,1, 32, 32, 192,384, 192,384, 8,4>
            <<<dim3(cdiv(192*(384/4),256),1,4*(32/8)), 256, 0, stream>>>(bufB, W[2], Bs[2], bufA);
        // L4: 32->32, s1
        conv_blk<3,1,1, 32, 32, 192,384, 192,384, 8,4>
            <<<dim3(cdiv(192*(384/4),256),1,4*(32/8)), 256, 0, stream>>>(bufA, W[3], Bs[3], bufB);
        // L5: 32->64, s2 -> 96x192
        conv_blk<3,2,1, 32, 64, 192,384,  96,192, 8,4>
            <<<dim3(cdiv(96*(192/4),256),1,4*(64/8)), 256, 0, stream>>>(bufB, W[4], Bs[4], bufA);
        // L6: 64->64, s1
        conv_blk<3,1,1, 64, 64,  96,192,  96,192, 8,4>
            <<<dim3(cdiv(96*(192/4),256),1,4*(64/8)), 256, 0, stream>>>(bufA, W[5], Bs[5], bufB);
        // L7: 64->96, s2 -> 48x96
        conv_blk<3,2,1, 64, 96,  96,192,  48, 96, 8,4>
            <<<dim3(cdiv(48*(96/4),256),1,4*(96/8)), 256, 0, stream>>>(bufB, W[6], Bs[6], bufA);
        // L8: 96->96, s1
        conv_blk<3,1,1, 96, 96,  48, 96,  48, 96, 8,4>
            <<<dim3(cdiv(48*(96/4),256),1,4*(96/8)), 256, 0, stream>>>(bufA, W[7], Bs[7], bufB);
        // L9: 96->128, s2 -> 24x48
        conv_blk<3,2,1, 96,128,  48, 96,  24, 48, 8,4>
            <<<dim3(cdiv(24*(48/4),256),1,4*(128/8)), 256, 0, stream>>>(bufB, W[8], Bs[8], bufA);
        // L10: 128->192, s2 -> 12x24
        conv_blk<3,2,1,128,192,  24, 48,  12, 24, 8,4>
            <<<dim3(cdiv(12*(24/4),256),1,4*(192/8)), 256, 0, stream>>>(bufA, W[9], Bs[9], fout);
    };

    chain(img1, f1);
    chain(img2, f2);

    warp_kernel<<<cdiv(4 * 192 * 288, 256), 256, 0, stream>>>(f2, flow, wrp, 192);
    corr_lrelu<<<cdiv(4 * 49 * 288, 256), 256, 0, stream>>>(f1, wrp, out, 192);
}